// Round 11
// baseline (152.997 us; speedup 1.0000x reference)
//
#include <hip/hip_runtime.h>
#include <hip/hip_bf16.h>

#define NV 16384
#define NC 16
#define NL 6
#define ND 64

typedef unsigned short u16;
typedef unsigned int u32;
typedef __attribute__((ext_vector_type(8))) short short8;
typedef __attribute__((ext_vector_type(4))) unsigned short u16x4;
typedef __attribute__((ext_vector_type(2))) int i32x2;
typedef __attribute__((ext_vector_type(4))) int i32x4;
typedef __attribute__((ext_vector_type(4))) float f32x4;

// ---- pbuf (fp32) offsets, pbuf = (float*)((char*)ws + 256) ----
#define PB_BN  0
#define PB_FE  64
#define PB_B1V 128
#define PB_B2V 192
#define PB_B1C 256
#define PB_B2C 320
// ---- bf16 regions, offsets in u16 elements from (u16*)ws ----
// BVS: clause-B swizzled [gk(12)][nt(8)][lane(64)][8]; elem = W{1,2}v[k][n&63],
//      k = gk*32 + (lane>>4)*8 + j, n = nt*16 + (lane&15)
#define U_BVS   896       // 49152
// BCS: var-B swizzled [ks(32)][nt(8)][lane(64)][8]  (natural K)
#define U_BCS   50048     // 131072
#define U_VARSB 185216    // [NV+1][64] bf16 vars; row NV = false_emb
#define U_NEGB  1233856   // [NV+1][64] bf16 negvar; row NV = true_emb
#define U_FIDX  2282496   // [NV][96] u16 fused row index (c*6+l)

__device__ __forceinline__ float ldbf(const u16* p, int i) {
  return __uint_as_float(((u32)p[i]) << 16);
}
__device__ __forceinline__ u16 f2b(float f) {  // RNE f32->bf16
  u32 x = __float_as_uint(f);
  return (u16)((x + 0x7FFF + ((x >> 16) & 1)) >> 16);
}
__device__ __forceinline__ int ldmask_nt(const void* p, int i, int bdt) {
  return bdt ? (int)__builtin_nontemporal_load((const signed char*)p + i)
             : __builtin_nontemporal_load((const int*)p + i);
}
__device__ __forceinline__ float ldf(const void* p, int i, int fdt) {
  return fdt ? ldbf((const u16*)p, i) : ((const float*)p)[i];
}
// async global->LDS, 16 B per lane; LDS dest = uniform base + lane*16
__device__ __forceinline__ void gll16(const u16* g, u16* l) {
  __builtin_amdgcn_global_load_lds(
      (const __attribute__((address_space(1))) u32*)(g),
      (__attribute__((address_space(3))) u32*)(l), 16, 0, 0);
}

// ---------- prep: weights + fused negvar/cvt/fidx; 346 blocks ----------
// bid 0: flags+params; 1..24: BVS; 25..88: BCS;
// 89..345: negvar+cvt (reads SOURCE vars once; writes VARSB+NEGB) and, for
//          nb<256, the FIDX rows nb*64..+63 (24 literals/thread, NT vector I/O)
__global__ __launch_bounds__(256) void k_prep(
    const void* vars, const int* __restrict__ lits, const void* negm, const void* vval,
    const void* Wn, const void* bn, const void* femb,
    const void* W1v, const void* b1v, const void* W2v, const void* b2v,
    const void* W1c, const void* b1c, const void* W2c, const void* b2c,
    int* flags, float* pbuf, u16* wsB) {
  __shared__ int s_cnt[4], s_big[4];
  __shared__ u16 wn[64 * 72];   // transposed Wn bf16, padded row 72 (negvar blocks)
  const int t = threadIdx.x;
  {
    const u32 w = ((const u32*)vars)[t];
    const u32 e = (w >> 7) & 0xFF;
    const unsigned long long bal = __ballot(e >= 0x6E && e <= 0x8E);
    const u32 bw = ((const u32*)vval)[t];
    const unsigned long long bb = __ballot(bw > 1u);
    if ((t & 63) == 0) { s_cnt[t >> 6] = __popcll(bal); s_big[t >> 6] = (bb != 0ull); }
  }
  __syncthreads();
  const int fdt = (s_cnt[0] + s_cnt[1] + s_cnt[2] + s_cnt[3]) >= 192;
  const int bdt = (s_big[0] | s_big[1] | s_big[2] | s_big[3]);
  const int bid = blockIdx.x;

  if (bid == 0) {
    if (t == 0) { flags[0] = fdt; flags[1] = bdt; }
    if (t < 64) {
      const void* src[6] = {bn, femb, b1v, b2v, b1c, b2c};
      const int off[6] = {PB_BN, PB_FE, PB_B1V, PB_B2V, PB_B1C, PB_B2C};
      for (int j = 0; j < 6; j++) pbuf[off[j] + t] = ldf(src[j], t, fdt);
      wsB[U_VARSB + NV * 64 + t] = fdt ? ((const u16*)femb)[t] : f2b(((const float*)femb)[t]);
    }
  } else if (bid < 25) {
    const int c = (bid - 1) * 256 + t;            // 0..6143
    const int ln = c & 63, nt = (c >> 6) & 7, ks = c >> 9;  // ks 0..11
    const int n = nt * 16 + (ln & 15);
    const void* src = (n < 64) ? W1v : W2v;
    const int kb = ks * 32 + (ln >> 4) * 8, n6 = n & 63;
    u16 o[8];
#pragma unroll
    for (int j = 0; j < 8; j++) o[j] = f2b(ldf(src, (kb + j) * 64 + n6, fdt));
    *(short8*)(wsB + U_BVS + c * 8) = *(short8*)o;
  } else if (bid < 89) {
    const int c = (bid - 25) * 256 + t;           // 0..16383
    const int ln = c & 63, nt = (c >> 6) & 7, ks = c >> 9;  // ks 0..31
    const int n = nt * 16 + (ln & 15);
    const void* src = (n < 64) ? W1c : W2c;
    const int kb = ks * 32 + (ln >> 4) * 8, n6 = n & 63;
    u16 o[8];
#pragma unroll
    for (int j = 0; j < 8; j++) o[j] = f2b(ldf(src, (kb + j) * 64 + n6, fdt));
    *(short8*)(wsB + U_BCS + c * 8) = *(short8*)o;
  } else {
    const int nb = bid - 89;                      // 0..256
    // ---- fidx for this block's 64 vars (nb<256): 24 literals/thread ----
    if (nb < 256) {
      const int eb = nb * 6144;                   // 64 rows * 96 lits
#pragma unroll
      for (int j8 = 0; j8 < 3; j8++) {
        const int i0 = eb + t * 24 + j8 * 8;
        const i32x4 l0 = __builtin_nontemporal_load((const i32x4*)((const int*)lits + i0));
        const i32x4 l1 = __builtin_nontemporal_load((const i32x4*)((const int*)lits + i0) + 1);
        int nm[8], vv[8];
        if (bdt) {
          const unsigned long long nmq =
              __builtin_nontemporal_load((const unsigned long long*)((const signed char*)negm + i0));
          const unsigned long long vvq =
              __builtin_nontemporal_load((const unsigned long long*)((const signed char*)vval + i0));
#pragma unroll
          for (int j = 0; j < 8; j++) {
            nm[j] = (int)((nmq >> (8 * j)) & 0xFF);
            vv[j] = (int)((vvq >> (8 * j)) & 0xFF);
          }
        } else {
          const i32x4 n0 = __builtin_nontemporal_load((const i32x4*)((const int*)negm + i0));
          const i32x4 n1 = __builtin_nontemporal_load((const i32x4*)((const int*)negm + i0) + 1);
          const i32x4 v0 = __builtin_nontemporal_load((const i32x4*)((const int*)vval + i0));
          const i32x4 v1 = __builtin_nontemporal_load((const i32x4*)((const int*)vval + i0) + 1);
#pragma unroll
          for (int j = 0; j < 4; j++) {
            nm[j] = n0[j]; nm[4 + j] = n1[j];
            vv[j] = v0[j]; vv[4 + j] = v1[j];
          }
        }
        u16 o[8];
#pragma unroll
        for (int j = 0; j < 8; j++) {
          const int idx = (j < 4) ? l0[j] : l1[j - 4];
          o[j] = (u16)(vv[j] ? (idx + (nm[j] ? (NV + 1) : 0)) : NV);
        }
        __builtin_nontemporal_store(*(short8*)o, (short8*)(wsB + U_FIDX + i0));
      }
    }
    // ---- fused negvar + cvt: 64 rows over NV+1 rows ----
    for (int e = t; e < 4096; e += 256) {
      const int k = e >> 6, n = e & 63;
      wn[n * 72 + k] = f2b(ldf(Wn, e, fdt));
    }
    __syncthreads();
    const int lane = t & 63, wv = t >> 6;
    const int col = lane & 15, quad = lane >> 4, q8 = quad * 8;
    const int rowbase = nb * 64 + wv * 16;
    f32x4 acc[4];
#pragma unroll
    for (int nt = 0; nt < 4; nt++) acc[nt] = (f32x4){0.f, 0.f, 0.f, 0.f};
    const int arow = min(rowbase + col, NV);
#pragma unroll
    for (int ks = 0; ks < 2; ks++) {
      short8 a;
      if (fdt) {
        const u16* ap = (arow == NV) ? (const u16*)femb : (const u16*)vars + arow * 64;
        a = *(const short8*)(ap + ks * 32 + q8);
      } else {
        const float* ap = (arow == NV) ? (const float*)femb : (const float*)vars + arow * 64;
        const f32x4 f0 = *(const f32x4*)(ap + ks * 32 + q8);
        const f32x4 f1 = *(const f32x4*)(ap + ks * 32 + q8 + 4);
#pragma unroll
        for (int j = 0; j < 4; j++) { a[j] = (short)f2b(f0[j]); a[4 + j] = (short)f2b(f1[j]); }
      }
      // cvt write (dup writes of the clamped femb row are same-value benign)
      *(short8*)(wsB + U_VARSB + arow * 64 + ks * 32 + q8) = a;
#pragma unroll
      for (int nt = 0; nt < 4; nt++) {
        const short8 b = *(const short8*)(&wn[(nt * 16 + col) * 72 + ks * 32 + q8]);
        acc[nt] = __builtin_amdgcn_mfma_f32_16x16x32_bf16(a, b, acc[nt], 0, 0, 0);
      }
    }
#pragma unroll
    for (int reg = 0; reg < 4; reg++) {
      const int r = rowbase + quad * 4 + reg;
      if (r <= NV) {
#pragma unroll
        for (int nt = 0; nt < 4; nt++) {
          const int d = nt * 16 + col;
          wsB[U_NEGB + r * 64 + d] = f2b(acc[nt][reg] + ldf(bn, d, fdt));
        }
      }
    }
  }
}

// ---------- fused clause + var combiner: 16 vars/block, 512 threads ----------
// (R9 kernel, verbatim: FIDX NT loads, depth-2 rotation, K-split phase 2)
__global__ __launch_bounds__(512, 4) void k_main(
    const void* __restrict__ vars, const void* __restrict__ cval,
    const float* __restrict__ pbuf, const int* __restrict__ flags,
    const u16* __restrict__ wsB, void* __restrict__ outv) {
  // phase 1: smem = B double-buffer [2][12288] (48 KB)
  // phase 2: smem[0..16383] = clause_emb [ks(32)][lane(64)][8] (32 KB);
  //          smem[16384..20479] = K-split reduce scratch (8 KB)
  __shared__ __align__(16) u16 smem[24576];
  __shared__ float ps[16][4];
  __shared__ int hcS[16];

  const int tid = threadIdx.x, lane = tid & 63, wv = tid >> 6;   // wv 0..7
  const int col = lane & 15, quad = lane >> 4, q8 = quad * 8;
  const int fdt = flags[0], bdt = flags[1];
  const int vbase = blockIdx.x * 16 + wv * 2;    // wave's 2 vars
  const int v0 = blockIdx.x * 16;

  // packed fidx: r2_[v4][i] = literals 2i,2i+1 of clause `col` of var vbase+v4
  u32 r2_[2][3];
#pragma unroll
  for (int v4 = 0; v4 < 2; v4++)
#pragma unroll
    for (int i = 0; i < 3; i++)
      r2_[v4][i] = __builtin_nontemporal_load(
          (const u32*)(wsB + U_FIDX + (vbase + v4) * 96 + col * 6 + i * 2));

  // cval for this wave's 2 vars (32 entries; lanes 32-63 duplicate)
  const int cv = ldmask_nt(cval, vbase * 16 + (lane & 31), bdt);
  const unsigned long long bal = __ballot(cv != 0);
  if (lane < 2) hcS[wv * 2 + lane] = ((bal >> (lane * 16)) & 0xFFFFull) != 0;

  f32x4 acc[2][8];
#pragma unroll
  for (int v4 = 0; v4 < 2; v4++)
#pragma unroll
    for (int nt = 0; nt < 8; nt++) acc[v4][nt] = (f32x4){0.f, 0.f, 0.f, 0.f};

  // stage quarter 0 into buf 0 (3 chunks of 1 KB per wave, 24 total)
#pragma unroll
  for (int j = 0; j < 3; j++) {
    const int cl = wv * 3 + j;
    gll16(wsB + U_BVS + cl * 512 + lane * 8, &smem[cl * 512]);
  }
  // depth-2 A prefetch via period-3 slot rotation (no copies)
  short8 a_[3][2];
#pragma unroll
  for (int v4 = 0; v4 < 2; v4++) {
    const int idx = (int)(r2_[v4][0] & 0xFFFFu);
    a_[0][v4] = *(const short8*)(wsB + U_VARSB + idx * 64 + q8);
    a_[1][v4] = *(const short8*)(wsB + U_VARSB + idx * 64 + 32 + q8);
  }
  __syncthreads();

  for (int q = 0; q < 4; q++) {
    if (q < 3) {
#pragma unroll
      for (int j = 0; j < 3; j++) {
        const int cl = wv * 3 + j;
        gll16(wsB + U_BVS + (q + 1) * 12288 + cl * 512 + lane * 8,
              &smem[((q + 1) & 1) * 12288 + cl * 512]);
      }
    }
#pragma unroll
    for (int ksl = 0; ksl < 3; ksl++) {
      const int gk = q * 3 + ksl;
      const int gn = gk + 2;                    // fill 2 ahead
      const int sf = (ksl + 2) % 3;             // fill slot (compile-time)
      if (gn < 12) {
        const int goff = (gn & 1) * 32 + q8;
        const int pi = gn >> 2, ph = (gn >> 1) & 1;
#pragma unroll
        for (int v4 = 0; v4 < 2; v4++) {
          const int idx = (int)((r2_[v4][pi] >> (ph * 16)) & 0xFFFFu);
          a_[sf][v4] = *(const short8*)(wsB + U_VARSB + idx * 64 + goff);
        }
      }
      __builtin_amdgcn_s_setprio(1);
#pragma unroll
      for (int nt = 0; nt < 8; nt++) {
        const short8 b = *(const short8*)(&smem[(q & 1) * 12288 + (ksl * 8 + nt) * 512 + lane * 8]);
#pragma unroll
        for (int v4 = 0; v4 < 2; v4++)
          acc[v4][nt] = __builtin_amdgcn_mfma_f32_16x16x32_bf16(a_[ksl][v4], b, acc[v4][nt], 0, 0, 0);
      }
      __builtin_amdgcn_s_setprio(0);
    }
    if (q < 3) __syncthreads();
  }
  __syncthreads();  // all waves done reading B before epilogue overwrites smem

  // phase-1 epilogue: normalize, clause-pad, write into smem (A layout for phase 2)
  {
    float b1l[4], b2l[4], truel[4];
#pragma unroll
    for (int nt = 0; nt < 4; nt++) {
      const int d = nt * 16 + col;
      b1l[nt] = pbuf[PB_B1V + d];
      b2l[nt] = pbuf[PB_B2V + d];
      truel[nt] = ldbf(wsB, U_NEGB + NV * 64 + d);
    }
#pragma unroll
    for (int v4 = 0; v4 < 2; v4++) {
      const u32 vmask = (u32)((bal >> (v4 * 16)) & 0xFFFFull);
      const int vloc = wv * 2 + v4;             // row 0..15 of the A tile
#pragma unroll
      for (int reg = 0; reg < 4; reg++) {
        const int c = quad * 4 + reg;
        float hh[4], ss = 0.f;
#pragma unroll
        for (int nt = 0; nt < 4; nt++) {
          hh[nt] = 1.0f / (1.0f + __expf(-(acc[v4][nt][reg] + b1l[nt]))) + acc[v4][nt + 4][reg] + b2l[nt];
          ss += hh[nt] * hh[nt];
        }
        ss += __shfl_xor(ss, 1, 64); ss += __shfl_xor(ss, 2, 64);
        ss += __shfl_xor(ss, 4, 64); ss += __shfl_xor(ss, 8, 64);
        const float sc = 1.0f / sqrtf(ss);
        const int valid = (vmask >> c) & 1;
#pragma unroll
        for (int nt = 0; nt < 4; nt++) {
          const float o = valid ? hh[nt] * sc : truel[nt];
          const int l2 = (nt * 2 + (col >> 3)) & 3;
          smem[(c * 2 + (nt >> 1)) * 512 + (l2 * 16 + vloc) * 8 + (col & 7)] = f2b(o);
        }
      }
    }
  }
  __syncthreads();

  // phase 2: var combiner, M=16, K=1024, K-split across wave halves.
  const int g = wv & 3, kh = wv >> 2;
  f32x4 acc1 = (f32x4){0.f, 0.f, 0.f, 0.f}, acc2 = (f32x4){0.f, 0.f, 0.f, 0.f};
#pragma unroll 8
  for (int ks = kh * 16; ks < kh * 16 + 16; ks++) {
    const short8 a = *(const short8*)(&smem[ks * 512 + lane * 8]);
    const short8 b1 = *(const short8*)(wsB + U_BCS + (ks * 8 + g) * 512 + lane * 8);
    const short8 b2 = *(const short8*)(wsB + U_BCS + (ks * 8 + g + 4) * 512 + lane * 8);
    acc1 = __builtin_amdgcn_mfma_f32_16x16x32_bf16(a, b1, acc1, 0, 0, 0);
    acc2 = __builtin_amdgcn_mfma_f32_16x16x32_bf16(a, b2, acc2, 0, 0, 0);
  }
  float* red = (float*)(smem + 16384);
  if (kh) {
    const int base = (g * 64 + lane) * 8;
    *(f32x4*)(red + base) = acc1;
    *(f32x4*)(red + base + 4) = acc2;
  }
  __syncthreads();

  float h[4];
  if (!kh) {
    const int base = (g * 64 + lane) * 8;
    acc1 += *(const f32x4*)(red + base);
    acc2 += *(const f32x4*)(red + base + 4);
    const int d = g * 16 + col;
    const float b1c_d = pbuf[PB_B1C + d], b2c_d = pbuf[PB_B2C + d];
#pragma unroll
    for (int reg = 0; reg < 4; reg++) {
      h[reg] = 1.0f / (1.0f + __expf(-(acc1[reg] + b1c_d))) + acc2[reg] + b2c_d;
      float ssp = h[reg] * h[reg];
      ssp += __shfl_xor(ssp, 1, 64); ssp += __shfl_xor(ssp, 2, 64);
      ssp += __shfl_xor(ssp, 4, 64); ssp += __shfl_xor(ssp, 8, 64);
      if (col == 0) ps[quad * 4 + reg][g] = ssp;
    }
  }
  __syncthreads();
  if (!kh) {
    const int d = g * 16 + col;
#pragma unroll
    for (int reg = 0; reg < 4; reg++) {
      const int r = quad * 4 + reg;
      const float tot = ps[r][0] + ps[r][1] + ps[r][2] + ps[r][3];
      float o = h[reg] * (1.0f / sqrtf(tot));
      const int oi = (v0 + r) * 64 + d;
      if (hcS[r]) {
        if (fdt) __builtin_nontemporal_store(f2b(o), &((u16*)outv)[oi]);
        else __builtin_nontemporal_store(o, &((float*)outv)[oi]);
      } else {
        if (fdt) __builtin_nontemporal_store(
            __builtin_nontemporal_load(&((const u16*)vars)[oi]), &((u16*)outv)[oi]);
        else __builtin_nontemporal_store(
            __builtin_nontemporal_load(&((const float*)vars)[oi]), &((float*)outv)[oi]);
      }
    }
  }
}

extern "C" void kernel_launch(void* const* d_in, const int* in_sizes, int n_in,
                              void* d_out, int out_size, void* d_ws, size_t ws_size,
                              hipStream_t stream) {
  const void* vars = d_in[0];
  const int* lits = (const int*)d_in[1];
  const void* negm = d_in[2];
  const void* vval = d_in[3];
  const void* cvalid = d_in[4];
  const void* Wn = d_in[5];
  const void* bn = d_in[6];
  const void* femb = d_in[7];
  const void* W1v = d_in[8];
  const void* b1v = d_in[9];
  const void* W2v = d_in[10];
  const void* b2v = d_in[11];
  const void* W1c = d_in[12];
  const void* b1c = d_in[13];
  const void* W2c = d_in[14];
  const void* b2c = d_in[15];

  int* flags = (int*)d_ws;
  float* pbuf = (float*)((char*)d_ws + 256);
  u16* wsB = (u16*)d_ws;

  k_prep<<<346, 256, 0, stream>>>(vars, lits, negm, vval, Wn, bn, femb,
                                  W1v, b1v, W2v, b2v, W1c, b1c, W2c, b2c,
                                  flags, pbuf, wsB);
  k_main<<<NV / 16, 512, 0, stream>>>(vars, cvalid, pbuf, flags, wsB, d_out);
}

// Round 12
// 150.082 us; speedup vs baseline: 1.0194x; 1.0194x over previous
//
#include <hip/hip_runtime.h>
#include <hip/hip_bf16.h>

#define NV 16384
#define NC 16
#define NL 6
#define ND 64

typedef unsigned short u16;
typedef unsigned int u32;
typedef __attribute__((ext_vector_type(8))) short short8;
typedef __attribute__((ext_vector_type(4))) unsigned short u16x4;
typedef __attribute__((ext_vector_type(2))) int i32x2;
typedef __attribute__((ext_vector_type(4))) int i32x4;
typedef __attribute__((ext_vector_type(4))) float f32x4;

// ---- pbuf (fp32) offsets, pbuf = (float*)((char*)ws + 256) ----
#define PB_BN  0
#define PB_FE  64
#define PB_B1V 128
#define PB_B2V 192
#define PB_B1C 256
#define PB_B2C 320
// ---- bf16 regions, offsets in u16 elements from (u16*)ws ----
// BVS: clause-B swizzled [gk(12)][nt(8)][lane(64)][8]; elem = W{1,2}v[k][n&63],
//      k = gk*32 + (lane>>4)*8 + j, n = nt*16 + (lane&15)
#define U_BVS   896       // 49152
// BCS: var-B swizzled [ks(32)][nt(8)][lane(64)][8]  (natural K)
#define U_BCS   50048     // 131072
#define U_VARSB 185216    // [NV+1][64] bf16 vars; row NV = false_emb
#define U_NEGB  1233856   // [NV+1][64] bf16 negvar; row NV = true_emb
#define U_FIDX  2282496   // [NV][96] u16 fused row index (c*6+l)

__device__ __forceinline__ float ldbf(const u16* p, int i) {
  return __uint_as_float(((u32)p[i]) << 16);
}
__device__ __forceinline__ u16 f2b(float f) {  // RNE f32->bf16
  u32 x = __float_as_uint(f);
  return (u16)((x + 0x7FFF + ((x >> 16) & 1)) >> 16);
}
__device__ __forceinline__ int ldmask_nt(const void* p, int i, int bdt) {
  return bdt ? (int)__builtin_nontemporal_load((const signed char*)p + i)
             : __builtin_nontemporal_load((const int*)p + i);
}
__device__ __forceinline__ float ldf(const void* p, int i, int fdt) {
  return fdt ? ldbf((const u16*)p, i) : ((const float*)p)[i];
}
// async global->LDS, 16 B per lane; LDS dest = uniform base + lane*16
__device__ __forceinline__ void gll16(const u16* g, u16* l) {
  __builtin_amdgcn_global_load_lds(
      (const __attribute__((address_space(1))) u32*)(g),
      (__attribute__((address_space(3))) u32*)(l), 16, 0, 0);
}

// ---------- prep: weights + negvar/cvt + DEDICATED fidx blocks; 1114 blocks ----------
// bid 0: flags+params; 1..24: BVS; 25..88: BCS;
// 89..345: negvar+cvt fused (reads SOURCE vars once; writes VARSB+NEGB);
// 346..1113: fidx (8 lits/thread, NT vector I/O) -- parallel with negvar blocks
__global__ __launch_bounds__(256) void k_prep(
    const void* vars, const int* __restrict__ lits, const void* negm, const void* vval,
    const void* Wn, const void* bn, const void* femb,
    const void* W1v, const void* b1v, const void* W2v, const void* b2v,
    const void* W1c, const void* b1c, const void* W2c, const void* b2c,
    int* flags, float* pbuf, u16* wsB) {
  __shared__ int s_cnt[4], s_big[4];
  __shared__ u16 wn[64 * 72];   // transposed Wn bf16, padded row 72 (negvar blocks)
  const int t = threadIdx.x;
  {
    const u32 w = ((const u32*)vars)[t];
    const u32 e = (w >> 7) & 0xFF;
    const unsigned long long bal = __ballot(e >= 0x6E && e <= 0x8E);
    const u32 bw = ((const u32*)vval)[t];
    const unsigned long long bb = __ballot(bw > 1u);
    if ((t & 63) == 0) { s_cnt[t >> 6] = __popcll(bal); s_big[t >> 6] = (bb != 0ull); }
  }
  __syncthreads();
  const int fdt = (s_cnt[0] + s_cnt[1] + s_cnt[2] + s_cnt[3]) >= 192;
  const int bdt = (s_big[0] | s_big[1] | s_big[2] | s_big[3]);
  const int bid = blockIdx.x;

  if (bid == 0) {
    if (t == 0) { flags[0] = fdt; flags[1] = bdt; }
    if (t < 64) {
      const void* src[6] = {bn, femb, b1v, b2v, b1c, b2c};
      const int off[6] = {PB_BN, PB_FE, PB_B1V, PB_B2V, PB_B1C, PB_B2C};
      for (int j = 0; j < 6; j++) pbuf[off[j] + t] = ldf(src[j], t, fdt);
      wsB[U_VARSB + NV * 64 + t] = fdt ? ((const u16*)femb)[t] : f2b(((const float*)femb)[t]);
    }
  } else if (bid < 25) {
    const int c = (bid - 1) * 256 + t;            // 0..6143
    const int ln = c & 63, nt = (c >> 6) & 7, ks = c >> 9;  // ks 0..11
    const int n = nt * 16 + (ln & 15);
    const void* src = (n < 64) ? W1v : W2v;
    const int kb = ks * 32 + (ln >> 4) * 8, n6 = n & 63;
    u16 o[8];
#pragma unroll
    for (int j = 0; j < 8; j++) o[j] = f2b(ldf(src, (kb + j) * 64 + n6, fdt));
    *(short8*)(wsB + U_BVS + c * 8) = *(short8*)o;
  } else if (bid < 89) {
    const int c = (bid - 25) * 256 + t;           // 0..16383
    const int ln = c & 63, nt = (c >> 6) & 7, ks = c >> 9;  // ks 0..31
    const int n = nt * 16 + (ln & 15);
    const void* src = (n < 64) ? W1c : W2c;
    const int kb = ks * 32 + (ln >> 4) * 8, n6 = n & 63;
    u16 o[8];
#pragma unroll
    for (int j = 0; j < 8; j++) o[j] = f2b(ldf(src, (kb + j) * 64 + n6, fdt));
    *(short8*)(wsB + U_BCS + c * 8) = *(short8*)o;
  } else if (bid < 346) {
    // ---- fused negvar + cvt: 64 rows/block over NV+1 rows ----
    const int nb = bid - 89;                      // 0..256
    for (int e = t; e < 4096; e += 256) {
      const int k = e >> 6, n = e & 63;
      wn[n * 72 + k] = f2b(ldf(Wn, e, fdt));
    }
    __syncthreads();
    const int lane = t & 63, wv = t >> 6;
    const int col = lane & 15, quad = lane >> 4, q8 = quad * 8;
    const int rowbase = nb * 64 + wv * 16;
    f32x4 acc[4];
#pragma unroll
    for (int nt = 0; nt < 4; nt++) acc[nt] = (f32x4){0.f, 0.f, 0.f, 0.f};
    const int arow = min(rowbase + col, NV);
#pragma unroll
    for (int ks = 0; ks < 2; ks++) {
      short8 a;
      if (fdt) {
        const u16* ap = (arow == NV) ? (const u16*)femb : (const u16*)vars + arow * 64;
        a = *(const short8*)(ap + ks * 32 + q8);
      } else {
        const float* ap = (arow == NV) ? (const float*)femb : (const float*)vars + arow * 64;
        const f32x4 f0 = *(const f32x4*)(ap + ks * 32 + q8);
        const f32x4 f1 = *(const f32x4*)(ap + ks * 32 + q8 + 4);
#pragma unroll
        for (int j = 0; j < 4; j++) { a[j] = (short)f2b(f0[j]); a[4 + j] = (short)f2b(f1[j]); }
      }
      // cvt write (dup writes of the clamped femb row are same-value benign)
      *(short8*)(wsB + U_VARSB + arow * 64 + ks * 32 + q8) = a;
#pragma unroll
      for (int nt = 0; nt < 4; nt++) {
        const short8 b = *(const short8*)(&wn[(nt * 16 + col) * 72 + ks * 32 + q8]);
        acc[nt] = __builtin_amdgcn_mfma_f32_16x16x32_bf16(a, b, acc[nt], 0, 0, 0);
      }
    }
#pragma unroll
    for (int reg = 0; reg < 4; reg++) {
      const int r = rowbase + quad * 4 + reg;
      if (r <= NV) {
#pragma unroll
        for (int nt = 0; nt < 4; nt++) {
          const int d = nt * 16 + col;
          wsB[U_NEGB + r * 64 + d] = f2b(acc[nt][reg] + ldf(bn, d, fdt));
        }
      }
    }
  } else {
    // ---- fidx: 8 literals/thread, NT vector loads/stores (parallel blocks) ----
    const int i0 = ((bid - 346) * 256 + t) * 8;
    const i32x4 l0 = __builtin_nontemporal_load((const i32x4*)((const int*)lits + i0));
    const i32x4 l1 = __builtin_nontemporal_load((const i32x4*)((const int*)lits + i0) + 1);
    int nm[8], vv[8];
    if (bdt) {
      const unsigned long long nmq =
          __builtin_nontemporal_load((const unsigned long long*)((const signed char*)negm + i0));
      const unsigned long long vvq =
          __builtin_nontemporal_load((const unsigned long long*)((const signed char*)vval + i0));
#pragma unroll
      for (int j = 0; j < 8; j++) {
        nm[j] = (int)((nmq >> (8 * j)) & 0xFF);
        vv[j] = (int)((vvq >> (8 * j)) & 0xFF);
      }
    } else {
      const i32x4 n0 = __builtin_nontemporal_load((const i32x4*)((const int*)negm + i0));
      const i32x4 n1 = __builtin_nontemporal_load((const i32x4*)((const int*)negm + i0) + 1);
      const i32x4 v0 = __builtin_nontemporal_load((const i32x4*)((const int*)vval + i0));
      const i32x4 v1 = __builtin_nontemporal_load((const i32x4*)((const int*)vval + i0) + 1);
#pragma unroll
      for (int j = 0; j < 4; j++) {
        nm[j] = n0[j]; nm[4 + j] = n1[j];
        vv[j] = v0[j]; vv[4 + j] = v1[j];
      }
    }
    u16 o[8];
#pragma unroll
    for (int j = 0; j < 8; j++) {
      const int idx = (j < 4) ? l0[j] : l1[j - 4];
      o[j] = (u16)(vv[j] ? (idx + (nm[j] ? (NV + 1) : 0)) : NV);
    }
    __builtin_nontemporal_store(*(short8*)o, (short8*)(wsB + U_FIDX + i0));
  }
}

// ---------- fused clause + var combiner: 16 vars/block, 512 threads ----------
// (R9 kernel, verbatim: FIDX NT loads, depth-2 rotation, K-split phase 2)
__global__ __launch_bounds__(512, 4) void k_main(
    const void* __restrict__ vars, const void* __restrict__ cval,
    const float* __restrict__ pbuf, const int* __restrict__ flags,
    const u16* __restrict__ wsB, void* __restrict__ outv) {
  // phase 1: smem = B double-buffer [2][12288] (48 KB)
  // phase 2: smem[0..16383] = clause_emb [ks(32)][lane(64)][8] (32 KB);
  //          smem[16384..20479] = K-split reduce scratch (8 KB)
  __shared__ __align__(16) u16 smem[24576];
  __shared__ float ps[16][4];
  __shared__ int hcS[16];

  const int tid = threadIdx.x, lane = tid & 63, wv = tid >> 6;   // wv 0..7
  const int col = lane & 15, quad = lane >> 4, q8 = quad * 8;
  const int fdt = flags[0], bdt = flags[1];
  const int vbase = blockIdx.x * 16 + wv * 2;    // wave's 2 vars
  const int v0 = blockIdx.x * 16;

  // packed fidx: r2_[v4][i] = literals 2i,2i+1 of clause `col` of var vbase+v4
  u32 r2_[2][3];
#pragma unroll
  for (int v4 = 0; v4 < 2; v4++)
#pragma unroll
    for (int i = 0; i < 3; i++)
      r2_[v4][i] = __builtin_nontemporal_load(
          (const u32*)(wsB + U_FIDX + (vbase + v4) * 96 + col * 6 + i * 2));

  // cval for this wave's 2 vars (32 entries; lanes 32-63 duplicate)
  const int cv = ldmask_nt(cval, vbase * 16 + (lane & 31), bdt);
  const unsigned long long bal = __ballot(cv != 0);
  if (lane < 2) hcS[wv * 2 + lane] = ((bal >> (lane * 16)) & 0xFFFFull) != 0;

  f32x4 acc[2][8];
#pragma unroll
  for (int v4 = 0; v4 < 2; v4++)
#pragma unroll
    for (int nt = 0; nt < 8; nt++) acc[v4][nt] = (f32x4){0.f, 0.f, 0.f, 0.f};

  // stage quarter 0 into buf 0 (3 chunks of 1 KB per wave, 24 total)
#pragma unroll
  for (int j = 0; j < 3; j++) {
    const int cl = wv * 3 + j;
    gll16(wsB + U_BVS + cl * 512 + lane * 8, &smem[cl * 512]);
  }
  // depth-2 A prefetch via period-3 slot rotation (no copies)
  short8 a_[3][2];
#pragma unroll
  for (int v4 = 0; v4 < 2; v4++) {
    const int idx = (int)(r2_[v4][0] & 0xFFFFu);
    a_[0][v4] = *(const short8*)(wsB + U_VARSB + idx * 64 + q8);
    a_[1][v4] = *(const short8*)(wsB + U_VARSB + idx * 64 + 32 + q8);
  }
  __syncthreads();

  for (int q = 0; q < 4; q++) {
    if (q < 3) {
#pragma unroll
      for (int j = 0; j < 3; j++) {
        const int cl = wv * 3 + j;
        gll16(wsB + U_BVS + (q + 1) * 12288 + cl * 512 + lane * 8,
              &smem[((q + 1) & 1) * 12288 + cl * 512]);
      }
    }
#pragma unroll
    for (int ksl = 0; ksl < 3; ksl++) {
      const int gk = q * 3 + ksl;
      const int gn = gk + 2;                    // fill 2 ahead
      const int sf = (ksl + 2) % 3;             // fill slot (compile-time)
      if (gn < 12) {
        const int goff = (gn & 1) * 32 + q8;
        const int pi = gn >> 2, ph = (gn >> 1) & 1;
#pragma unroll
        for (int v4 = 0; v4 < 2; v4++) {
          const int idx = (int)((r2_[v4][pi] >> (ph * 16)) & 0xFFFFu);
          a_[sf][v4] = *(const short8*)(wsB + U_VARSB + idx * 64 + goff);
        }
      }
      __builtin_amdgcn_s_setprio(1);
#pragma unroll
      for (int nt = 0; nt < 8; nt++) {
        const short8 b = *(const short8*)(&smem[(q & 1) * 12288 + (ksl * 8 + nt) * 512 + lane * 8]);
#pragma unroll
        for (int v4 = 0; v4 < 2; v4++)
          acc[v4][nt] = __builtin_amdgcn_mfma_f32_16x16x32_bf16(a_[ksl][v4], b, acc[v4][nt], 0, 0, 0);
      }
      __builtin_amdgcn_s_setprio(0);
    }
    if (q < 3) __syncthreads();
  }
  __syncthreads();  // all waves done reading B before epilogue overwrites smem

  // phase-1 epilogue: normalize, clause-pad, write into smem (A layout for phase 2)
  {
    float b1l[4], b2l[4], truel[4];
#pragma unroll
    for (int nt = 0; nt < 4; nt++) {
      const int d = nt * 16 + col;
      b1l[nt] = pbuf[PB_B1V + d];
      b2l[nt] = pbuf[PB_B2V + d];
      truel[nt] = ldbf(wsB, U_NEGB + NV * 64 + d);
    }
#pragma unroll
    for (int v4 = 0; v4 < 2; v4++) {
      const u32 vmask = (u32)((bal >> (v4 * 16)) & 0xFFFFull);
      const int vloc = wv * 2 + v4;             // row 0..15 of the A tile
#pragma unroll
      for (int reg = 0; reg < 4; reg++) {
        const int c = quad * 4 + reg;
        float hh[4], ss = 0.f;
#pragma unroll
        for (int nt = 0; nt < 4; nt++) {
          hh[nt] = 1.0f / (1.0f + __expf(-(acc[v4][nt][reg] + b1l[nt]))) + acc[v4][nt + 4][reg] + b2l[nt];
          ss += hh[nt] * hh[nt];
        }
        ss += __shfl_xor(ss, 1, 64); ss += __shfl_xor(ss, 2, 64);
        ss += __shfl_xor(ss, 4, 64); ss += __shfl_xor(ss, 8, 64);
        const float sc = 1.0f / sqrtf(ss);
        const int valid = (vmask >> c) & 1;
#pragma unroll
        for (int nt = 0; nt < 4; nt++) {
          const float o = valid ? hh[nt] * sc : truel[nt];
          const int l2 = (nt * 2 + (col >> 3)) & 3;
          smem[(c * 2 + (nt >> 1)) * 512 + (l2 * 16 + vloc) * 8 + (col & 7)] = f2b(o);
        }
      }
    }
  }
  __syncthreads();

  // phase 2: var combiner, M=16, K=1024, K-split across wave halves.
  const int g = wv & 3, kh = wv >> 2;
  f32x4 acc1 = (f32x4){0.f, 0.f, 0.f, 0.f}, acc2 = (f32x4){0.f, 0.f, 0.f, 0.f};
#pragma unroll 8
  for (int ks = kh * 16; ks < kh * 16 + 16; ks++) {
    const short8 a = *(const short8*)(&smem[ks * 512 + lane * 8]);
    const short8 b1 = *(const short8*)(wsB + U_BCS + (ks * 8 + g) * 512 + lane * 8);
    const short8 b2 = *(const short8*)(wsB + U_BCS + (ks * 8 + g + 4) * 512 + lane * 8);
    acc1 = __builtin_amdgcn_mfma_f32_16x16x32_bf16(a, b1, acc1, 0, 0, 0);
    acc2 = __builtin_amdgcn_mfma_f32_16x16x32_bf16(a, b2, acc2, 0, 0, 0);
  }
  float* red = (float*)(smem + 16384);
  if (kh) {
    const int base = (g * 64 + lane) * 8;
    *(f32x4*)(red + base) = acc1;
    *(f32x4*)(red + base + 4) = acc2;
  }
  __syncthreads();

  float h[4];
  if (!kh) {
    const int base = (g * 64 + lane) * 8;
    acc1 += *(const f32x4*)(red + base);
    acc2 += *(const f32x4*)(red + base + 4);
    const int d = g * 16 + col;
    const float b1c_d = pbuf[PB_B1C + d], b2c_d = pbuf[PB_B2C + d];
#pragma unroll
    for (int reg = 0; reg < 4; reg++) {
      h[reg] = 1.0f / (1.0f + __expf(-(acc1[reg] + b1c_d))) + acc2[reg] + b2c_d;
      float ssp = h[reg] * h[reg];
      ssp += __shfl_xor(ssp, 1, 64); ssp += __shfl_xor(ssp, 2, 64);
      ssp += __shfl_xor(ssp, 4, 64); ssp += __shfl_xor(ssp, 8, 64);
      if (col == 0) ps[quad * 4 + reg][g] = ssp;
    }
  }
  __syncthreads();
  if (!kh) {
    const int d = g * 16 + col;
#pragma unroll
    for (int reg = 0; reg < 4; reg++) {
      const int r = quad * 4 + reg;
      const float tot = ps[r][0] + ps[r][1] + ps[r][2] + ps[r][3];
      float o = h[reg] * (1.0f / sqrtf(tot));
      const int oi = (v0 + r) * 64 + d;
      if (hcS[r]) {
        if (fdt) __builtin_nontemporal_store(f2b(o), &((u16*)outv)[oi]);
        else __builtin_nontemporal_store(o, &((float*)outv)[oi]);
      } else {
        if (fdt) __builtin_nontemporal_store(
            __builtin_nontemporal_load(&((const u16*)vars)[oi]), &((u16*)outv)[oi]);
        else __builtin_nontemporal_store(
            __builtin_nontemporal_load(&((const float*)vars)[oi]), &((float*)outv)[oi]);
      }
    }
  }
}

extern "C" void kernel_launch(void* const* d_in, const int* in_sizes, int n_in,
                              void* d_out, int out_size, void* d_ws, size_t ws_size,
                              hipStream_t stream) {
  const void* vars = d_in[0];
  const int* lits = (const int*)d_in[1];
  const void* negm = d_in[2];
  const void* vval = d_in[3];
  const void* cvalid = d_in[4];
  const void* Wn = d_in[5];
  const void* bn = d_in[6];
  const void* femb = d_in[7];
  const void* W1v = d_in[8];
  const void* b1v = d_in[9];
  const void* W2v = d_in[10];
  const void* b2v = d_in[11];
  const void* W1c = d_in[12];
  const void* b1c = d_in[13];
  const void* W2c = d_in[14];
  const void* b2c = d_in[15];

  int* flags = (int*)d_ws;
  float* pbuf = (float*)((char*)d_ws + 256);
  u16* wsB = (u16*)d_ws;

  k_prep<<<1114, 256, 0, stream>>>(vars, lits, negm, vval, Wn, bn, femb,
                                   W1v, b1v, W2v, b2v, W1c, b1c, W2c, b2c,
                                   flags, pbuf, wsB);
  k_main<<<NV / 16, 512, 0, stream>>>(vars, cvalid, pbuf, flags, wsB, d_out);
}